// Round 3
// baseline (566.848 us; speedup 1.0000x reference)
//
#include <hip/hip_runtime.h>
#include <stdint.h>

#define HH 2048
#define BB 16384

typedef int v4i __attribute__((ext_vector_type(4)));

__device__ __forceinline__ int clip127(int v){
  v = v > 127 ? 127 : v;
  return v < -127 ? -127 : v;
}
// floor division by 720 (matches Python //)
__device__ __forceinline__ int fdiv720(int r){
  int q = r / 720;
  return q - ((r - q * 720) < 0 ? 1 : 0);
}

// Pack int32 (values in [-127,127]) -> int8. 16 elems / thread / iter.
__global__ void pack_i32_to_i8(const int* __restrict__ src, int8_t* __restrict__ dst, int n16){
  int stride = gridDim.x * blockDim.x;
  for (int i = blockIdx.x * blockDim.x + threadIdx.x; i < n16; i += stride){
    const int4* s = (const int4*)src + (size_t)i * 4;
    int4 a = s[0], b = s[1], c = s[2], d = s[3];
    int4 o;
    o.x = (a.x & 255) | ((a.y & 255) << 8) | ((a.z & 255) << 16) | (a.w << 24);
    o.y = (b.x & 255) | ((b.y & 255) << 8) | ((b.z & 255) << 16) | (b.w << 24);
    o.z = (c.x & 255) | ((c.y & 255) << 8) | ((c.z & 255) << 16) | (c.w << 24);
    o.w = (d.x & 255) | ((d.y & 255) << 8) | ((d.z & 255) << 16) | (d.w << 24);
    ((int4*)dst)[i] = o;
  }
}

// Duplicate first half of d_out into second half (int4).
__global__ void dup_out(const int* __restrict__ src, int* __restrict__ dst, int n4){
  int stride = gridDim.x * blockDim.x;
  for (int i = blockIdx.x * blockDim.x + threadIdx.x; i < n4; i += stride)
    ((int4*)dst)[i] = ((const int4*)src)[i];
}

// Fused dual-GEMM: acc1 = A1 @ B1^T, acc2 = A2 @ B2^T over the same 128x128
// output tile. B1/B2 are (out,in) row-major weights -> both operands K-contiguous.
// PHASE 1: f_t = clip(clip(acc1//720)+clip(acc2//720)+bias);
//          fbuf[idx] = f_t+127 (int32);  g8out[idx] = clip(((f_t+127)*state)>>8)
// PHASE 2: h_t = ...; ns = clip(state + ((fbuf[idx]*(h_t-state))>>8));
//          fbuf[idx] = ns (int32; read-then-write same element, same thread)
template<int PHASE>
__global__ __launch_bounds__(256, 2)
void gemm_fused(const int8_t* __restrict__ A1, const int8_t* __restrict__ A2,
                const int8_t* __restrict__ B1, const int8_t* __restrict__ B2,
                const int* __restrict__ bias,
                const int8_t* __restrict__ state8,
                int* fbuf,
                int8_t* __restrict__ g8out)
{
  // 4 tiles of 128 rows x 64 bytes (K) = 8KB each: A1,A2,B1,B2
  __shared__ __align__(16) int8_t lds[4 * 8192];
  const int tid  = threadIdx.x;
  const int lane = tid & 63;
  const int wave = tid >> 6;
  const int wrow = wave >> 1, wcol = wave & 1;
  const int bid  = blockIdx.x;
  const int rowbase = (bid >> 4) * 128;
  const int colbase = (bid & 15) * 128;

  v4i accA[4][4], accB[4][4];
  const v4i vzero = {0, 0, 0, 0};
#pragma unroll
  for (int m = 0; m < 4; m++)
#pragma unroll
    for (int n = 0; n < 4; n++){ accA[m][n] = vzero; accB[m][n] = vzero; }

  const int srow   = tid >> 2;   // 0..63 (row within 64-row staging pass)
  const int schunk = tid & 3;    // 16B chunk within 64B row
  const int chunk  = lane >> 4;  // frag-read 16B chunk
  const int rl     = lane & 15;

  for (int kk = 0; kk < HH / 64; ++kk){
    const int k0 = kk * 64;
    // ---- stage 4 tiles: linear LDS dest + inverse-swizzled global source ----
#pragma unroll
    for (int p = 0; p < 2; p++){
      const int row = p * 64 + srow;
      const int swc = schunk ^ ((row >> 1) & 3);       // XOR swizzle (involution)
      const size_t aoff = (size_t)(rowbase + row) * HH + k0 + swc * 16;
      const size_t boff = (size_t)(colbase + row) * HH + k0 + swc * 16;
      const int ldst = p * 4096 + tid * 16;
      __builtin_amdgcn_global_load_lds((const __attribute__((address_space(1))) void*)(A1 + aoff),
                                       (__attribute__((address_space(3))) void*)(lds + ldst), 16, 0, 0);
      __builtin_amdgcn_global_load_lds((const __attribute__((address_space(1))) void*)(A2 + aoff),
                                       (__attribute__((address_space(3))) void*)(lds + 8192 + ldst), 16, 0, 0);
      __builtin_amdgcn_global_load_lds((const __attribute__((address_space(1))) void*)(B1 + boff),
                                       (__attribute__((address_space(3))) void*)(lds + 16384 + ldst), 16, 0, 0);
      __builtin_amdgcn_global_load_lds((const __attribute__((address_space(1))) void*)(B2 + boff),
                                       (__attribute__((address_space(3))) void*)(lds + 24576 + ldst), 16, 0, 0);
    }
    __syncthreads();

    // ---- pair 1: A1 x B1 -> accA ----
    {
      v4i af[4], bf[4];
#pragma unroll
      for (int m = 0; m < 4; m++){
        int row = wrow * 64 + m * 16 + rl;
        af[m] = *(const v4i*)(lds + row * 64 + ((chunk ^ ((row >> 1) & 3)) << 4));
      }
#pragma unroll
      for (int n = 0; n < 4; n++){
        int row = wcol * 64 + n * 16 + rl;
        bf[n] = *(const v4i*)(lds + 16384 + row * 64 + ((chunk ^ ((row >> 1) & 3)) << 4));
      }
#pragma unroll
      for (int m = 0; m < 4; m++)
#pragma unroll
        for (int n = 0; n < 4; n++)
          accA[m][n] = __builtin_amdgcn_mfma_i32_16x16x64_i8(af[m], bf[n], accA[m][n], 0, 0, 0);
    }
    // ---- pair 2: A2 x B2 -> accB ----
    {
      v4i af[4], bf[4];
#pragma unroll
      for (int m = 0; m < 4; m++){
        int row = wrow * 64 + m * 16 + rl;
        af[m] = *(const v4i*)(lds + 8192 + row * 64 + ((chunk ^ ((row >> 1) & 3)) << 4));
      }
#pragma unroll
      for (int n = 0; n < 4; n++){
        int row = wcol * 64 + n * 16 + rl;
        bf[n] = *(const v4i*)(lds + 24576 + row * 64 + ((chunk ^ ((row >> 1) & 3)) << 4));
      }
#pragma unroll
      for (int m = 0; m < 4; m++)
#pragma unroll
        for (int n = 0; n < 4; n++)
          accB[m][n] = __builtin_amdgcn_mfma_i32_16x16x64_i8(af[m], bf[n], accB[m][n], 0, 0, 0);
    }
    __syncthreads();
  }

  // ---- epilogue: C/D layout col=lane&15, row=(lane>>4)*4+reg ----
  const int q = lane >> 4;
#pragma unroll
  for (int m = 0; m < 4; m++){
#pragma unroll
    for (int n = 0; n < 4; n++){
      const int gcol = colbase + wcol * 64 + n * 16 + rl;
      const int bval = bias[gcol];
#pragma unroll
      for (int r = 0; r < 4; r++){
        const int grow = rowbase + wrow * 64 + m * 16 + q * 4 + r;
        const size_t idx = (size_t)grow * HH + gcol;
        const int v1 = clip127(fdiv720(accA[m][n][r]));
        const int v2 = clip127(fdiv720(accB[m][n][r]));
        const int t  = clip127(v1 + v2 + bval);   // f_t or h_tilde
        const int st = state8[idx];
        if (PHASE == 1){
          const int fg = t + 127;
          const int gated = clip127((fg * st) >> 8);
          fbuf[idx]  = fg;                 // int32 store
          g8out[idx] = (int8_t)gated;
        } else {
          const int fg   = fbuf[idx];
          const int diff = t - st;
          const int ns   = clip127(st + ((fg * diff) >> 8));
          fbuf[idx] = ns;                  // int32 store (output 0)
        }
      }
    }
  }
}

extern "C" void kernel_launch(void* const* d_in, const int* in_sizes, int n_in,
                              void* d_out, int out_size, void* d_ws, size_t ws_size,
                              hipStream_t stream){
  const int* x  = (const int*)d_in[0];
  const int* st = (const int*)d_in[1];
  const int* Wf = (const int*)d_in[2];
  const int* Uf = (const int*)d_in[3];
  const int* bf = (const int*)d_in[4];
  const int* Wh = (const int*)d_in[5];
  const int* Uh = (const int*)d_in[6];
  const int* bh = (const int*)d_in[7];

  const size_t NBH = (size_t)BB * HH;   // 33,554,432 elements
  const size_t NW  = (size_t)HH * HH;   //  4,194,304 elements

  // d_out is an int32 buffer of 2*NBH elements (tuple output, int8->int32).
  // Scratch lives in d_out's SECOND HALF (128 MiB, rewritten by dup_out at
  // the end). First half holds f_gate (int32) then new_state (int32).
  // Budget: 32+32+32+16 = 112 MiB <= 128 MiB. d_ws unused.
  int*    fbuf = (int*)d_out;                         // first half
  int8_t* base = (int8_t*)d_out + (size_t)NBH * 4;    // second half
  int8_t* x8  = base;                    // 32 MiB
  int8_t* s8  = x8 + NBH;                // 32 MiB
  int8_t* g8  = s8 + NBH;                // 32 MiB
  int8_t* wf8 = g8 + NBH;                // 4 MiB
  int8_t* uf8 = wf8 + NW;                // 4 MiB
  int8_t* wh8 = uf8 + NW;                // 4 MiB
  int8_t* uh8 = wh8 + NW;                // 4 MiB  (ends at 112 MiB)

  pack_i32_to_i8<<<2048, 256, 0, stream>>>(x,  x8,  (int)(NBH / 16));
  pack_i32_to_i8<<<2048, 256, 0, stream>>>(st, s8,  (int)(NBH / 16));
  pack_i32_to_i8<<<1024, 256, 0, stream>>>(Wf, wf8, (int)(NW / 16));
  pack_i32_to_i8<<<1024, 256, 0, stream>>>(Uf, uf8, (int)(NW / 16));
  pack_i32_to_i8<<<1024, 256, 0, stream>>>(Wh, wh8, (int)(NW / 16));
  pack_i32_to_i8<<<1024, 256, 0, stream>>>(Uh, uh8, (int)(NW / 16));

  // grid: (16384/128) * (2048/128) = 128 * 16 = 2048 blocks
  gemm_fused<1><<<2048, 256, 0, stream>>>(x8, s8, wf8, uf8, bf, s8, fbuf, g8);
  gemm_fused<2><<<2048, 256, 0, stream>>>(x8, g8, wh8, uh8, bh, s8, fbuf, nullptr);

  // Duplicate new_state into the tuple's second output slot.
  dup_out<<<2048, 256, 0, stream>>>((const int*)d_out,
                                    (int*)d_out + NBH, (int)(NBH / 4));
}